// Round 2
// baseline (1598.251 us; speedup 1.0000x reference)
//
#include <hip/hip_runtime.h>
#include <hip/hip_bf16.h>

// ---------------- constants ----------------
#define B_SZ   4
#define SEQ    2048
#define DM     1024
#define DIN    2048
#define DST    64
#define NH     32
#define HD     64
#define CONVD  2176
#define DPROJ  4256   // 2*DIN + 2*DST + NH
#define NPAD1  4352   // DPROJ padded to 34*128
#define MROWS  (B_SZ*SEQ)  // 8192

typedef __attribute__((ext_vector_type(8))) __bf16 bf16x8;
typedef __attribute__((ext_vector_type(4))) __bf16 bf16x4;
typedef __attribute__((ext_vector_type(4))) float  floatx4;

// ---------------- fp32 -> bf16 convert (x) ----------------
__global__ __launch_bounds__(256) void cvt_bf16_kernel(const float* __restrict__ src,
                                                       __bf16* __restrict__ dst, int n4) {
    int i = blockIdx.x * 256 + threadIdx.x;
    if (i >= n4) return;
    float4 v = ((const float4*)src)[i];
    bf16x4 o;
    o[0] = (__bf16)v.x; o[1] = (__bf16)v.y; o[2] = (__bf16)v.z; o[3] = (__bf16)v.w;
    *(bf16x4*)(dst + (size_t)i * 4) = o;
}

// ---------------- transpose + cast: dst[c][r] = bf16(src[r][c]) (0 for c>=C) ----
__global__ __launch_bounds__(256) void transpose_cvt_kernel(const float* __restrict__ src,
                                                            __bf16* __restrict__ dst,
                                                            int R, int C, int Crows) {
    __shared__ float tile[32][33];
    int r0 = blockIdx.x * 32, c0 = blockIdx.y * 32;
    int tx = threadIdx.x & 31, ty = threadIdx.x >> 5;  // 32 x 8
    #pragma unroll
    for (int i = 0; i < 4; i++) {
        int r = r0 + ty + i * 8, c = c0 + tx;
        float v = (r < R && c < C) ? src[(size_t)r * C + c] : 0.f;
        tile[ty + i * 8][tx] = v;
    }
    __syncthreads();
    #pragma unroll
    for (int i = 0; i < 4; i++) {
        int cc = c0 + ty + i * 8, rr = r0 + tx;
        if (cc < Crows && rr < R)
            dst[(size_t)cc * R + rr] = (__bf16)tile[tx][ty + i * 8];
    }
}

// ---------------- bf16 MFMA GEMM: C[M][N] = A[M][K] * Bt[N][K]^T ----------------
// STORE_BF16=1 -> bf16 output (Cb), 0 -> fp32 output (Cf)
template<int STORE_BF16>
__global__ __launch_bounds__(256) void gemm_bt_kernel(const __bf16* __restrict__ A,
                                                      const __bf16* __restrict__ Bt,
                                                      float* __restrict__ Cf,
                                                      __bf16* __restrict__ Cb,
                                                      int M, int N, int K) {
    __shared__ __align__(16) __bf16 As[128][32];
    __shared__ __align__(16) __bf16 Bs[128][32];
    const int tid = threadIdx.x;
    const int m0 = blockIdx.x * 128, n0 = blockIdx.y * 128;
    const int wave = tid >> 6, lane = tid & 63;
    const int wm = (wave & 1) << 6, wn = (wave >> 1) << 6;
    const int lm = lane & 15, lq = lane >> 4;

    floatx4 acc[4][4] = {};

    for (int k0 = 0; k0 < K; k0 += 32) {
        #pragma unroll
        for (int r = 0; r < 2; r++) {
            int c = tid + (r << 8);              // 512 chunks of 8 bf16
            int row = c >> 2, off = (c & 3) << 3;
            *(uint4*)(&As[row][off]) = *(const uint4*)(&A[(size_t)(m0 + row) * K + k0 + off]);
            *(uint4*)(&Bs[row][off]) = *(const uint4*)(&Bt[(size_t)(n0 + row) * K + k0 + off]);
        }
        __syncthreads();
        bf16x8 af[4], bfr[4];
        #pragma unroll
        for (int i = 0; i < 4; i++)
            af[i] = *(const bf16x8*)(&As[wm + i * 16 + lm][lq * 8]);
        #pragma unroll
        for (int i = 0; i < 4; i++)
            bfr[i] = *(const bf16x8*)(&Bs[wn + i * 16 + lm][lq * 8]);
        #pragma unroll
        for (int mi = 0; mi < 4; mi++)
            #pragma unroll
            for (int ni = 0; ni < 4; ni++)
                acc[mi][ni] = __builtin_amdgcn_mfma_f32_16x16x32_bf16(af[mi], bfr[ni], acc[mi][ni], 0, 0, 0);
        __syncthreads();
    }

    #pragma unroll
    for (int mi = 0; mi < 4; mi++) {
        #pragma unroll
        for (int r = 0; r < 4; r++) {
            int row = m0 + wm + mi * 16 + lq * 4 + r;
            #pragma unroll
            for (int ni = 0; ni < 4; ni++) {
                int col = n0 + wn + ni * 16 + lm;
                if (col < N) {
                    if (STORE_BF16) Cb[(size_t)row * N + col] = (__bf16)acc[mi][ni][r];
                    else            Cf[(size_t)row * N + col] = acc[mi][ni][r];
                }
            }
        }
    }
}

// ---------------- fp32 dt projection: dt_raw[row][h] = x[row][:] . W_in[:, 4224+h] ----
__global__ __launch_bounds__(256) void dt_proj_kernel(const float* __restrict__ x,
                                                      const float* __restrict__ W_in,
                                                      float* __restrict__ dt_raw) {
    __shared__ float xs[DM];
    int row = blockIdx.x;
    int tid = threadIdx.x;
    const float* xr = x + (size_t)row * DM;
    for (int i = tid; i < DM; i += 256) xs[i] = xr[i];
    __syncthreads();
    int h = tid >> 3, part = tid & 7;     // 32 heads x 8 partials
    float ss = 0.f;
    const float* wcol = W_in + (size_t)(2 * DIN + 2 * DST) + h;  // W_in[k][4224+h]
    for (int k = part * 128; k < part * 128 + 128; k++)
        ss += xs[k] * wcol[(size_t)k * DPROJ];
    ss += __shfl_xor(ss, 1);
    ss += __shfl_xor(ss, 2);
    ss += __shfl_xor(ss, 4);
    if (part == 0) dt_raw[(size_t)row * NH + h] = ss;
}

// ---------------- depthwise causal conv (width 4) + silu (bf16 in/out, fp32 math) ----
__global__ __launch_bounds__(256) void conv_silu_kernel(const __bf16* __restrict__ zx,
                                                        const float* __restrict__ cw,
                                                        const float* __restrict__ cb,
                                                        __bf16* __restrict__ out) {
    int c = blockIdx.x * 256 + threadIdx.x;
    if (c >= CONVD) return;
    int g = blockIdx.y;            // (b, t-group of 4)
    int b = g >> 9;                // 512 groups per batch
    int t0 = (g & 511) << 2;
    const __bf16* base = zx + ((size_t)b * SEQ) * DPROJ + DIN + c;
    float xbuf[7];
    #pragma unroll
    for (int i = 0; i < 7; i++) {
        int tt = t0 + i - 3;
        xbuf[i] = (tt >= 0) ? (float)base[(size_t)tt * DPROJ] : 0.f;
    }
    float w0 = cw[c * 4 + 0], w1 = cw[c * 4 + 1], w2 = cw[c * 4 + 2], w3 = cw[c * 4 + 3];
    float bias = cb[c];
    __bf16* orow = out + ((size_t)b * SEQ + t0) * CONVD + c;
    #pragma unroll
    for (int s = 0; s < 4; s++) {
        float v = bias + w0 * xbuf[s] + w1 * xbuf[s + 1] + w2 * xbuf[s + 2] + w3 * xbuf[s + 3];
        orow[(size_t)s * CONVD] = (__bf16)(v / (1.f + __expf(-v)));
    }
}

// ---------------- sequential SSM scan ----------------
// block = one (b,h); 256 threads: p = wave*16 + (lane>>2), ng = lane&3 (16 states each)
__global__ __launch_bounds__(256) void ssm_scan_kernel(const __bf16* __restrict__ xc,   // [B*L][2176] bf16
                                                       const float* __restrict__ dt_raw,// [B*L][32]
                                                       const float* __restrict__ dt_bias,
                                                       const float* __restrict__ A_log,
                                                       const float* __restrict__ Dv,
                                                       __bf16* __restrict__ y) {        // [B*L][2048] bf16
    const int blk = blockIdx.x;       // b*32 + h
    const int b = blk >> 5, h = blk & 31;
    const int tid = threadIdx.x;
    const int wave = tid >> 6, lane = tid & 63;
    const int p = wave * 16 + (lane >> 2);
    const int ng = lane & 3;
    const float Ah = -__expf(A_log[h]);
    const float Dh = Dv[h];
    const float dtb = dt_bias[h];

    __shared__ float sx[16][64], sB[16][64], sC[16][64], sdt[16];
    float hreg[16];
    #pragma unroll
    for (int i = 0; i < 16; i++) hreg[i] = 0.f;

    const __bf16* xb = xc + (size_t)b * SEQ * CONVD;
    for (int t0 = 0; t0 < SEQ; t0 += 16) {
        for (int idx = tid; idx < 16 * 192; idx += 256) {
            int s = idx / 192, j = idx % 192;
            const __bf16* rowp = xb + (size_t)(t0 + s) * CONVD;
            if (j < 64)       sx[s][j]       = (float)rowp[h * 64 + j];
            else if (j < 128) sB[s][j - 64]  = (float)rowp[DIN + (j - 64)];
            else              sC[s][j - 128] = (float)rowp[DIN + DST + (j - 128)];
        }
        if (tid < 16) {
            float u = dt_raw[((size_t)b * SEQ + t0 + tid) * NH + h] + dtb;
            sdt[tid] = fmaxf(u, 0.f) + log1pf(__expf(-fabsf(u)));  // softplus
        }
        __syncthreads();
        for (int s = 0; s < 16; s++) {
            float dtt = sdt[s];
            float dA = __expf(dtt * Ah);
            float xv = sx[s][p];
            float dtx = dtt * xv;
            float ysum = 0.f;
            #pragma unroll
            for (int n = 0; n < 16; n++) {
                float Bv = sB[s][ng * 16 + n];
                float Cv = sC[s][ng * 16 + n];
                hreg[n] = fmaf(hreg[n], dA, dtx * Bv);
                ysum = fmaf(hreg[n], Cv, ysum);
            }
            ysum += __shfl_xor(ysum, 1);
            ysum += __shfl_xor(ysum, 2);
            if (ng == 0)
                y[((size_t)b * SEQ + t0 + s) * DIN + h * 64 + p] = (__bf16)fmaf(Dh, xv, ysum);
        }
        __syncthreads();
    }
}

// ---------------- gate (silu(z)) + RMSNorm, IN PLACE on y (bf16) ----------------
__global__ __launch_bounds__(256) void gate_norm_kernel(__bf16* __restrict__ y,
                                                        const __bf16* __restrict__ zx,
                                                        const float* __restrict__ nw) {
    int row = blockIdx.x;
    int tid = threadIdx.x;
    __bf16* yr = y + (size_t)row * DIN;
    const __bf16* zr = zx + (size_t)row * DPROJ;   // z = first 2048 cols
    float v[8]; float ss = 0.f;
    #pragma unroll
    for (int i = 0; i < 8; i++) {
        int c = i * 256 + tid;
        float z = (float)zr[c];
        float val = (float)yr[c] * (z / (1.f + __expf(-z)));
        v[i] = val; ss += val * val;
    }
    __shared__ float red[4];
    int lane = tid & 63, wave = tid >> 6;
    for (int o = 32; o > 0; o >>= 1) ss += __shfl_down(ss, o);
    if (lane == 0) red[wave] = ss;
    __syncthreads();
    float tot = red[0] + red[1] + red[2] + red[3];
    float scale = rsqrtf(tot * (1.f / (float)DIN) + 1e-5f);
    #pragma unroll
    for (int i = 0; i < 8; i++) {
        int c = i * 256 + tid;
        yr[c] = (__bf16)(v[i] * scale * nw[c]);
    }
}

// ---------------- launch ----------------
extern "C" void kernel_launch(void* const* d_in, const int* in_sizes, int n_in,
                              void* d_out, int out_size, void* d_ws, size_t ws_size,
                              hipStream_t stream) {
    const float* x       = (const float*)d_in[0];
    const float* W_in    = (const float*)d_in[1];
    const float* conv_w  = (const float*)d_in[2];
    const float* conv_b  = (const float*)d_in[3];
    const float* dt_bias = (const float*)d_in[4];
    const float* A_log   = (const float*)d_in[5];
    const float* Dv      = (const float*)d_in[6];
    const float* norm_w  = (const float*)d_in[7];
    const float* W_out   = (const float*)d_in[8];
    float* out = (float*)d_out;   // reference output dtype is fp32

    char* ws = (char*)d_ws;
    size_t off = 0;
    auto take = [&](size_t bytes) { void* p = ws + off; off = (off + bytes + 255) & ~(size_t)255; return p; };
    __bf16* xbf    = (__bf16*)take((size_t)MROWS * DM * 2);          // 16.8 MB
    __bf16* WinT   = (__bf16*)take((size_t)NPAD1 * DM * 2);          //  8.9 MB
    __bf16* WoutT  = (__bf16*)take((size_t)DM * DIN * 2);            //  4.2 MB
    __bf16* zx     = (__bf16*)take((size_t)MROWS * DPROJ * 2);       // 69.7 MB
    __bf16* xc     = (__bf16*)take((size_t)MROWS * CONVD * 2);       // 35.7 MB
    __bf16* yf     = (__bf16*)take((size_t)MROWS * DIN * 2);         // 33.6 MB
    float*  dtraw  = (float*) take((size_t)MROWS * NH * 4);          //  1.0 MB
    (void)ws_size;                                                    // total ~170 MB

    // 1. x -> bf16
    cvt_bf16_kernel<<<dim3((MROWS * DM / 4 + 255) / 256), 256, 0, stream>>>(x, xbf, MROWS * DM / 4);
    // 2. W_in^T (pad to 4352 rows of zeros), W_out^T
    transpose_cvt_kernel<<<dim3(DM / 32, NPAD1 / 32), 256, 0, stream>>>(W_in, WinT, DM, DPROJ, NPAD1);
    transpose_cvt_kernel<<<dim3(DIN / 32, DM / 32), 256, 0, stream>>>(W_out, WoutT, DIN, DM, DM);
    // 3. GEMM1: zx = x @ W_in  (bf16 out)
    gemm_bt_kernel<1><<<dim3(MROWS / 128, (DPROJ + 127) / 128), 256, 0, stream>>>(
        xbf, WinT, nullptr, zx, MROWS, DPROJ, DM);
    // 4. dt columns in fp32 (precision-sensitive: feeds exp(dt*A))
    dt_proj_kernel<<<dim3(MROWS), 256, 0, stream>>>(x, W_in, dtraw);
    // 5. depthwise conv + silu
    conv_silu_kernel<<<dim3((CONVD + 255) / 256, B_SZ * SEQ / 4), 256, 0, stream>>>(zx, conv_w, conv_b, xc);
    // 6. SSM scan
    ssm_scan_kernel<<<dim3(B_SZ * NH), 256, 0, stream>>>(xc, dtraw, dt_bias, A_log, Dv, yf);
    // 7. gate + RMSNorm (in place on yf)
    gate_norm_kernel<<<dim3(MROWS), 256, 0, stream>>>(yf, zx, norm_w);
    // 8. GEMM2: out = yf @ W_out (fp32 out)
    gemm_bt_kernel<0><<<dim3(MROWS / 128, DM / 128), 256, 0, stream>>>(
        yf, WoutT, out, nullptr, MROWS, DM, DIN);
}

// Round 3
// 753.805 us; speedup vs baseline: 2.1202x; 2.1202x over previous
//
#include <hip/hip_runtime.h>
#include <hip/hip_bf16.h>

// ---------------- constants ----------------
#define B_SZ   4
#define SEQ    2048
#define DM     1024
#define DIN    2048
#define DST    64
#define NH     32
#define HD     64
#define CONVD  2176
#define DPROJ  4256   // 2*DIN + 2*DST + NH
#define NPAD1  4352   // DPROJ padded to 34*128
#define MROWS  (B_SZ*SEQ)  // 8192
#define QC     64     // scan chunk length
#define NC     (SEQ/QC)   // 32 chunks

typedef __attribute__((ext_vector_type(8))) __bf16 bf16x8;
typedef __attribute__((ext_vector_type(4))) __bf16 bf16x4;
typedef __attribute__((ext_vector_type(4))) float  floatx4;

// ---------------- fp32 -> bf16 convert (x) ----------------
__global__ __launch_bounds__(256) void cvt_bf16_kernel(const float* __restrict__ src,
                                                       __bf16* __restrict__ dst, int n4) {
    int i = blockIdx.x * 256 + threadIdx.x;
    if (i >= n4) return;
    float4 v = ((const float4*)src)[i];
    bf16x4 o;
    o[0] = (__bf16)v.x; o[1] = (__bf16)v.y; o[2] = (__bf16)v.z; o[3] = (__bf16)v.w;
    *(bf16x4*)(dst + (size_t)i * 4) = o;
}

// ---------------- transpose + cast: dst[c][r] = bf16(src[r][c]) (0 for c>=C) ----
__global__ __launch_bounds__(256) void transpose_cvt_kernel(const float* __restrict__ src,
                                                            __bf16* __restrict__ dst,
                                                            int R, int C, int Crows) {
    __shared__ float tile[32][33];
    int r0 = blockIdx.x * 32, c0 = blockIdx.y * 32;
    int tx = threadIdx.x & 31, ty = threadIdx.x >> 5;  // 32 x 8
    #pragma unroll
    for (int i = 0; i < 4; i++) {
        int r = r0 + ty + i * 8, c = c0 + tx;
        float v = (r < R && c < C) ? src[(size_t)r * C + c] : 0.f;
        tile[ty + i * 8][tx] = v;
    }
    __syncthreads();
    #pragma unroll
    for (int i = 0; i < 4; i++) {
        int cc = c0 + ty + i * 8, rr = r0 + tx;
        if (cc < Crows && rr < R)
            dst[(size_t)cc * R + rr] = (__bf16)tile[tx][ty + i * 8];
    }
}

// ---------------- bf16 MFMA GEMM: C[M][N] = A[M][K] * Bt[N][K]^T ----------------
template<int STORE_BF16>
__global__ __launch_bounds__(256) void gemm_bt_kernel(const __bf16* __restrict__ A,
                                                      const __bf16* __restrict__ Bt,
                                                      float* __restrict__ Cf,
                                                      __bf16* __restrict__ Cb,
                                                      int M, int N, int K) {
    __shared__ __align__(16) __bf16 As[128][32];
    __shared__ __align__(16) __bf16 Bs[128][32];
    const int tid = threadIdx.x;
    const int m0 = blockIdx.x * 128, n0 = blockIdx.y * 128;
    const int wave = tid >> 6, lane = tid & 63;
    const int wm = (wave & 1) << 6, wn = (wave >> 1) << 6;
    const int lm = lane & 15, lq = lane >> 4;

    floatx4 acc[4][4] = {};

    for (int k0 = 0; k0 < K; k0 += 32) {
        #pragma unroll
        for (int r = 0; r < 2; r++) {
            int c = tid + (r << 8);              // 512 chunks of 8 bf16
            int row = c >> 2, off = (c & 3) << 3;
            *(uint4*)(&As[row][off]) = *(const uint4*)(&A[(size_t)(m0 + row) * K + k0 + off]);
            *(uint4*)(&Bs[row][off]) = *(const uint4*)(&Bt[(size_t)(n0 + row) * K + k0 + off]);
        }
        __syncthreads();
        bf16x8 af[4], bfr[4];
        #pragma unroll
        for (int i = 0; i < 4; i++)
            af[i] = *(const bf16x8*)(&As[wm + i * 16 + lm][lq * 8]);
        #pragma unroll
        for (int i = 0; i < 4; i++)
            bfr[i] = *(const bf16x8*)(&Bs[wn + i * 16 + lm][lq * 8]);
        #pragma unroll
        for (int mi = 0; mi < 4; mi++)
            #pragma unroll
            for (int ni = 0; ni < 4; ni++)
                acc[mi][ni] = __builtin_amdgcn_mfma_f32_16x16x32_bf16(af[mi], bfr[ni], acc[mi][ni], 0, 0, 0);
        __syncthreads();
    }

    #pragma unroll
    for (int mi = 0; mi < 4; mi++) {
        #pragma unroll
        for (int r = 0; r < 4; r++) {
            int row = m0 + wm + mi * 16 + lq * 4 + r;
            #pragma unroll
            for (int ni = 0; ni < 4; ni++) {
                int col = n0 + wn + ni * 16 + lm;
                if (col < N) {
                    if (STORE_BF16) Cb[(size_t)row * N + col] = (__bf16)acc[mi][ni][r];
                    else            Cf[(size_t)row * N + col] = acc[mi][ni][r];
                }
            }
        }
    }
}

// ---------------- fp32 dt projection: dt_raw[row][h] = x[row][:] . W_in[:, 4224+h] ----
__global__ __launch_bounds__(256) void dt_proj_kernel(const float* __restrict__ x,
                                                      const float* __restrict__ W_in,
                                                      float* __restrict__ dt_raw) {
    __shared__ float xs[DM];
    int row = blockIdx.x;
    int tid = threadIdx.x;
    const float* xr = x + (size_t)row * DM;
    for (int i = tid; i < DM; i += 256) xs[i] = xr[i];
    __syncthreads();
    int h = tid >> 3, part = tid & 7;     // 32 heads x 8 partials
    float ss = 0.f;
    const float* wcol = W_in + (size_t)(2 * DIN + 2 * DST) + h;  // W_in[k][4224+h]
    for (int k = part * 128; k < part * 128 + 128; k++)
        ss += xs[k] * wcol[(size_t)k * DPROJ];
    ss += __shfl_xor(ss, 1);
    ss += __shfl_xor(ss, 2);
    ss += __shfl_xor(ss, 4);
    if (part == 0) dt_raw[(size_t)row * NH + h] = ss;
}

// ---------------- depthwise causal conv (width 4) + silu (bf16 in/out, fp32 math) ----
__global__ __launch_bounds__(256) void conv_silu_kernel(const __bf16* __restrict__ zx,
                                                        const float* __restrict__ cw,
                                                        const float* __restrict__ cb,
                                                        __bf16* __restrict__ out) {
    int c = blockIdx.x * 256 + threadIdx.x;
    if (c >= CONVD) return;
    int g = blockIdx.y;            // (b, t-group of 4)
    int b = g >> 9;                // 512 groups per batch
    int t0 = (g & 511) << 2;
    const __bf16* base = zx + ((size_t)b * SEQ) * DPROJ + DIN + c;
    float xbuf[7];
    #pragma unroll
    for (int i = 0; i < 7; i++) {
        int tt = t0 + i - 3;
        xbuf[i] = (tt >= 0) ? (float)base[(size_t)tt * DPROJ] : 0.f;
    }
    float w0 = cw[c * 4 + 0], w1 = cw[c * 4 + 1], w2 = cw[c * 4 + 2], w3 = cw[c * 4 + 3];
    float bias = cb[c];
    __bf16* orow = out + ((size_t)b * SEQ + t0) * CONVD + c;
    #pragma unroll
    for (int s = 0; s < 4; s++) {
        float v = bias + w0 * xbuf[s] + w1 * xbuf[s + 1] + w2 * xbuf[s + 2] + w3 * xbuf[s + 3];
        orow[(size_t)s * CONVD] = (__bf16)(v / (1.f + __expf(-v)));
    }
}

// ---------------- dt prep: softplus + per-chunk inclusive cumsum of dt*A ----------------
// block = (b,h); wave handles chunks wave, wave+4, ...; lane = position in chunk (QC=64)
__global__ __launch_bounds__(256) void dt_prep_kernel(const float* __restrict__ dtraw,
                                                      const float* __restrict__ dt_bias,
                                                      const float* __restrict__ A_log,
                                                      float* __restrict__ dtv,
                                                      float* __restrict__ cum) {
    int blk = blockIdx.x;          // b*NH + h
    int b = blk >> 5, h = blk & 31;
    int wave = threadIdx.x >> 6, lane = threadIdx.x & 63;
    float Ah = -__expf(A_log[h]);
    float dtb = dt_bias[h];
    for (int c = wave; c < NC; c += 4) {
        int t = c * QC + lane;
        float u = dtraw[((size_t)b * SEQ + t) * NH + h] + dtb;
        float d = fmaxf(u, 0.f) + log1pf(__expf(-fabsf(u)));  // softplus, fp32
        float s = d * Ah;
        #pragma unroll
        for (int o = 1; o < 64; o <<= 1) {        // inclusive wave prefix sum
            float v = __shfl_up(s, o);
            if (lane >= o) s += v;
        }
        size_t idx = (size_t)blk * SEQ + t;
        dtv[idx] = d;
        cum[idx] = s;
    }
}

// ---------------- pass 1: per-chunk local scan (zero init state) ----------------
// block = (b,c,h); 256 threads: p = wave*16 + (lane>>2), ng = lane&3 (16 states each)
__global__ __launch_bounds__(256) void scan_chunk_kernel(const __bf16* __restrict__ xc,
                                                         const float* __restrict__ dtv,
                                                         const float* __restrict__ A_log,
                                                         const float* __restrict__ Dv,
                                                         __bf16* __restrict__ y,
                                                         __bf16* __restrict__ Sbuf) {
    const int blk = blockIdx.x;          // ((b*NC)+c)*NH + h
    const int h = blk & 31;
    const int bc = blk >> 5;
    const int c = bc & (NC - 1), b = bc >> 5;
    const int tid = threadIdx.x;
    const int wave = tid >> 6, lane = tid & 63;
    const int p = wave * 16 + (lane >> 2);
    const int ng = lane & 3;
    const float Ah = -__expf(A_log[h]);
    const float Dh = Dv[h];

    __shared__ float sx[16][64], sB[16][64], sC[16][64], sdt[16];
    float hreg[16];
    #pragma unroll
    for (int i = 0; i < 16; i++) hreg[i] = 0.f;

    const __bf16* xb = xc + ((size_t)b * SEQ + (size_t)c * QC) * CONVD;
    const float* dtp = dtv + ((size_t)b * NH + h) * SEQ + (size_t)c * QC;

    for (int t0 = 0; t0 < QC; t0 += 16) {
        for (int idx = tid; idx < 16 * 192; idx += 256) {
            int s = idx / 192, j = idx % 192;
            const __bf16* rowp = xb + (size_t)(t0 + s) * CONVD;
            if (j < 64)       sx[s][j]       = (float)rowp[h * 64 + j];
            else if (j < 128) sB[s][j - 64]  = (float)rowp[DIN + (j - 64)];
            else              sC[s][j - 128] = (float)rowp[DIN + DST + (j - 128)];
        }
        if (tid < 16) sdt[tid] = dtp[t0 + tid];
        __syncthreads();
        for (int s = 0; s < 16; s++) {
            float dtt = sdt[s];
            float dA = __expf(dtt * Ah);
            float xv = sx[s][p];
            float dtx = dtt * xv;
            float ysum = 0.f;
            #pragma unroll
            for (int n = 0; n < 16; n++) {
                float Bv = sB[s][ng * 16 + n];
                float Cv = sC[s][ng * 16 + n];
                hreg[n] = fmaf(hreg[n], dA, dtx * Bv);
                ysum = fmaf(hreg[n], Cv, ysum);
            }
            ysum += __shfl_xor(ysum, 1);
            ysum += __shfl_xor(ysum, 2);
            if (ng == 0)
                y[((size_t)b * SEQ + (size_t)c * QC + t0 + s) * DIN + h * 64 + p] = (__bf16)fmaf(Dh, xv, ysum);
        }
        __syncthreads();
    }
    // write local chunk state
    __bf16* Sp = Sbuf + (size_t)blk * (HD * DST) + p * DST + ng * 16;
    #pragma unroll
    for (int n = 0; n < 16; n++) Sp[n] = (__bf16)hreg[n];
}

// ---------------- pass 2: inter-chunk state recurrence (in place) ----------------
// block = (b,h); thread owns 16 contiguous elems of the 64x64 state
__global__ __launch_bounds__(256) void state_scan_kernel(__bf16* __restrict__ Sbuf,
                                                         const float* __restrict__ cum) {
    int blk = blockIdx.x;          // b*NH + h
    int b = blk >> 5, h = blk & 31;
    int off = threadIdx.x * 16;
    float run[16];
    #pragma unroll
    for (int n = 0; n < 16; n++) run[n] = 0.f;
    for (int c = 0; c < NC; c++) {
        __bf16* Sp = Sbuf + ((size_t)(b * NC + c) * NH + h) * (HD * DST) + off;
        float tmp[16];
        #pragma unroll
        for (int n = 0; n < 16; n++) tmp[n] = (float)Sp[n];
        #pragma unroll
        for (int n = 0; n < 16; n++) Sp[n] = (__bf16)run[n];   // slot c <- state before chunk c
        float P = __expf(cum[(size_t)blk * SEQ + c * QC + QC - 1]);
        #pragma unroll
        for (int n = 0; n < 16; n++) run[n] = fmaf(run[n], P, tmp[n]);
    }
}

// ---------------- pass 3: apply inter-chunk state to y ----------------
// block = (b,c,h); same thread mapping as pass 1
__global__ __launch_bounds__(256) void state_apply_kernel(const __bf16* __restrict__ Sbuf,
                                                          const __bf16* __restrict__ xc,
                                                          const float* __restrict__ cum,
                                                          __bf16* __restrict__ y) {
    const int blk = blockIdx.x;          // ((b*NC)+c)*NH + h
    const int h = blk & 31;
    const int bc = blk >> 5;
    const int c = bc & (NC - 1), b = bc >> 5;
    const int tid = threadIdx.x;
    const int wave = tid >> 6, lane = tid & 63;
    const int p = wave * 16 + (lane >> 2);
    const int ng = lane & 3;

    float S[16];
    const __bf16* Sp = Sbuf + (size_t)blk * (HD * DST) + p * DST + ng * 16;
    #pragma unroll
    for (int n = 0; n < 16; n++) S[n] = (float)Sp[n];

    __shared__ float sC[16][64], scum[16];
    const float* cump = cum + ((size_t)b * NH + h) * SEQ + (size_t)c * QC;

    for (int t0 = 0; t0 < QC; t0 += 16) {
        for (int idx = tid; idx < 16 * 64; idx += 256) {
            int s = idx >> 6, j = idx & 63;
            sC[s][j] = (float)xc[((size_t)b * SEQ + (size_t)c * QC + t0 + s) * CONVD + DIN + DST + j];
        }
        if (tid < 16) scum[tid] = cump[t0 + tid];
        __syncthreads();
        for (int s = 0; s < 16; s++) {
            float part = 0.f;
            #pragma unroll
            for (int n = 0; n < 16; n++)
                part = fmaf(S[n], sC[s][ng * 16 + n], part);
            part += __shfl_xor(part, 1);
            part += __shfl_xor(part, 2);
            if (ng == 0) {
                size_t yi = ((size_t)b * SEQ + (size_t)c * QC + t0 + s) * DIN + h * 64 + p;
                y[yi] = (__bf16)((float)y[yi] + __expf(scum[s]) * part);
            }
        }
        __syncthreads();
    }
}

// ---------------- gate (silu(z)) + RMSNorm, IN PLACE on y (bf16) ----------------
__global__ __launch_bounds__(256) void gate_norm_kernel(__bf16* __restrict__ y,
                                                        const __bf16* __restrict__ zx,
                                                        const float* __restrict__ nw) {
    int row = blockIdx.x;
    int tid = threadIdx.x;
    __bf16* yr = y + (size_t)row * DIN;
    const __bf16* zr = zx + (size_t)row * DPROJ;   // z = first 2048 cols
    float v[8]; float ss = 0.f;
    #pragma unroll
    for (int i = 0; i < 8; i++) {
        int c = i * 256 + tid;
        float z = (float)zr[c];
        float val = (float)yr[c] * (z / (1.f + __expf(-z)));
        v[i] = val; ss += val * val;
    }
    __shared__ float red[4];
    int lane = tid & 63, wave = tid >> 6;
    for (int o = 32; o > 0; o >>= 1) ss += __shfl_down(ss, o);
    if (lane == 0) red[wave] = ss;
    __syncthreads();
    float tot = red[0] + red[1] + red[2] + red[3];
    float scale = rsqrtf(tot * (1.f / (float)DIN) + 1e-5f);
    #pragma unroll
    for (int i = 0; i < 8; i++) {
        int c = i * 256 + tid;
        yr[c] = (__bf16)(v[i] * scale * nw[c]);
    }
}

// ---------------- launch ----------------
extern "C" void kernel_launch(void* const* d_in, const int* in_sizes, int n_in,
                              void* d_out, int out_size, void* d_ws, size_t ws_size,
                              hipStream_t stream) {
    const float* x       = (const float*)d_in[0];
    const float* W_in    = (const float*)d_in[1];
    const float* conv_w  = (const float*)d_in[2];
    const float* conv_b  = (const float*)d_in[3];
    const float* dt_bias = (const float*)d_in[4];
    const float* A_log   = (const float*)d_in[5];
    const float* Dv      = (const float*)d_in[6];
    const float* norm_w  = (const float*)d_in[7];
    const float* W_out   = (const float*)d_in[8];
    float* out = (float*)d_out;

    char* ws = (char*)d_ws;
    size_t off = 0;
    auto take = [&](size_t bytes) { void* p = ws + off; off = (off + bytes + 255) & ~(size_t)255; return p; };
    __bf16* xbf    = (__bf16*)take((size_t)MROWS * DM * 2);          // 16.8 MB
    __bf16* WinT   = (__bf16*)take((size_t)NPAD1 * DM * 2);          //  8.9 MB
    __bf16* WoutT  = (__bf16*)take((size_t)DM * DIN * 2);            //  4.2 MB
    __bf16* zx     = (__bf16*)take((size_t)MROWS * DPROJ * 2);       // 69.7 MB
    __bf16* xc     = (__bf16*)take((size_t)MROWS * CONVD * 2);       // 35.7 MB
    __bf16* yf     = (__bf16*)take((size_t)MROWS * DIN * 2);         // 33.6 MB
    float*  dtraw  = (float*) take((size_t)MROWS * NH * 4);          //  1.0 MB
    float*  dtv    = (float*) take((size_t)B_SZ * NH * SEQ * 4);     //  1.0 MB
    float*  cum    = (float*) take((size_t)B_SZ * NH * SEQ * 4);     //  1.0 MB
    __bf16* Sbuf   = (__bf16*)take((size_t)B_SZ * NC * NH * HD * DST * 2); // 33.6 MB
    (void)ws_size;                                                    // total ~206 MB

    // 1. x -> bf16
    cvt_bf16_kernel<<<dim3((MROWS * DM / 4 + 255) / 256), 256, 0, stream>>>(x, xbf, MROWS * DM / 4);
    // 2. W_in^T (pad to 4352 rows of zeros), W_out^T
    transpose_cvt_kernel<<<dim3(DM / 32, NPAD1 / 32), 256, 0, stream>>>(W_in, WinT, DM, DPROJ, NPAD1);
    transpose_cvt_kernel<<<dim3(DIN / 32, DM / 32), 256, 0, stream>>>(W_out, WoutT, DIN, DM, DM);
    // 3. GEMM1: zx = x @ W_in  (bf16 out)
    gemm_bt_kernel<1><<<dim3(MROWS / 128, (DPROJ + 127) / 128), 256, 0, stream>>>(
        xbf, WinT, nullptr, zx, MROWS, DPROJ, DM);
    // 4. dt columns in fp32 (precision-sensitive: feeds exp(dt*A))
    dt_proj_kernel<<<dim3(MROWS), 256, 0, stream>>>(x, W_in, dtraw);
    // 5. depthwise conv + silu
    conv_silu_kernel<<<dim3((CONVD + 255) / 256, B_SZ * SEQ / 4), 256, 0, stream>>>(zx, conv_w, conv_b, xc);
    // 6. dt prep: softplus + per-chunk cumsum
    dt_prep_kernel<<<dim3(B_SZ * NH), 256, 0, stream>>>(dtraw, dt_bias, A_log, dtv, cum);
    // 7. pass 1: per-chunk local scan (4096 blocks)
    scan_chunk_kernel<<<dim3(B_SZ * NC * NH), 256, 0, stream>>>(xc, dtv, A_log, Dv, yf, Sbuf);
    // 8. pass 2: inter-chunk state recurrence
    state_scan_kernel<<<dim3(B_SZ * NH), 256, 0, stream>>>(Sbuf, cum);
    // 9. pass 3: apply inter-chunk states to y
    state_apply_kernel<<<dim3(B_SZ * NC * NH), 256, 0, stream>>>(Sbuf, xc, cum, yf);
    // 10. gate + RMSNorm (in place on yf)
    gate_norm_kernel<<<dim3(MROWS), 256, 0, stream>>>(yf, zx, norm_w);
    // 11. GEMM2: out = yf @ W_out (fp32 out)
    gemm_bt_kernel<0><<<dim3(MROWS / 128, DM / 128), 256, 0, stream>>>(
        yf, WoutT, out, nullptr, MROWS, DM, DIN);
}

// Round 4
// 545.785 us; speedup vs baseline: 2.9284x; 1.3811x over previous
//
#include <hip/hip_runtime.h>
#include <hip/hip_bf16.h>

// ---------------- constants ----------------
#define B_SZ   4
#define SEQ    2048
#define DM     1024
#define DIN    2048
#define DST    64
#define NH     32
#define HD     64
#define CONVD  2176
#define DPROJ  4256   // 2*DIN + 2*DST + NH
#define NPAD1  4352   // DPROJ padded to 34*128
#define MROWS  (B_SZ*SEQ)  // 8192
#define QC     64     // scan chunk length
#define NC     (SEQ/QC)   // 32 chunks

typedef __attribute__((ext_vector_type(8))) __bf16 bf16x8;
typedef __attribute__((ext_vector_type(4))) __bf16 bf16x4;
typedef __attribute__((ext_vector_type(4))) float  floatx4;

// ---------------- compact dt-weight: dtWc[k*32+h] = W_in[k][4224+h] ----------------
__global__ __launch_bounds__(256) void dtw_prep_kernel(const float* __restrict__ W_in,
                                                       float* __restrict__ dtWc) {
    int idx = blockIdx.x * 256 + threadIdx.x;     // 32768 total
    int k = idx >> 5, h = idx & 31;
    dtWc[idx] = W_in[(size_t)k * DPROJ + 2 * DIN + 2 * DST + h];
}

// ---------------- fused: x -> bf16 copy + fp32 dt projection ----------------
// block = 4 rows; 256 threads
__global__ __launch_bounds__(256) void cvt_dt_kernel(const float* __restrict__ x,
                                                     const float* __restrict__ dtWc,
                                                     __bf16* __restrict__ xbf,
                                                     float* __restrict__ dtraw) {
    __shared__ float xs[4][DM];
    __shared__ float red[4][8][32];
    const int row0 = blockIdx.x * 4;
    const int tid = threadIdx.x;
    #pragma unroll
    for (int r = 0; r < 4; r++) {
        float4 v = ((const float4*)(x + (size_t)(row0 + r) * DM))[tid];
        bf16x4 o;
        o[0] = (__bf16)v.x; o[1] = (__bf16)v.y; o[2] = (__bf16)v.z; o[3] = (__bf16)v.w;
        *(bf16x4*)(xbf + (size_t)(row0 + r) * DM + tid * 4) = o;
        xs[r][tid * 4 + 0] = v.x; xs[r][tid * 4 + 1] = v.y;
        xs[r][tid * 4 + 2] = v.z; xs[r][tid * 4 + 3] = v.w;
    }
    __syncthreads();
    const int part = tid >> 5, h = tid & 31;
    const float* wb = dtWc + part * 128 * 32 + h;
    const int kb = part * 128;
    float s0 = 0.f, s1 = 0.f, s2 = 0.f, s3 = 0.f;
    for (int j = 0; j < 128; j++) {
        float w = wb[j * 32];
        s0 = fmaf(xs[0][kb + j], w, s0);
        s1 = fmaf(xs[1][kb + j], w, s1);
        s2 = fmaf(xs[2][kb + j], w, s2);
        s3 = fmaf(xs[3][kb + j], w, s3);
    }
    red[0][part][h] = s0; red[1][part][h] = s1;
    red[2][part][h] = s2; red[3][part][h] = s3;
    __syncthreads();
    if (tid < 128) {
        int r = tid >> 5, hh = tid & 31;
        float s = 0.f;
        #pragma unroll
        for (int p = 0; p < 8; p++) s += red[r][p][hh];
        dtraw[(size_t)(row0 + r) * NH + hh] = s;
    }
}

// ---------------- transpose + cast: dst[c][r] = bf16(src[r][c]) (0 for c>=C) ----
__global__ __launch_bounds__(256) void transpose_cvt_kernel(const float* __restrict__ src,
                                                            __bf16* __restrict__ dst,
                                                            int R, int C, int Crows) {
    __shared__ float tile[32][33];
    int r0 = blockIdx.x * 32, c0 = blockIdx.y * 32;
    int tx = threadIdx.x & 31, ty = threadIdx.x >> 5;  // 32 x 8
    #pragma unroll
    for (int i = 0; i < 4; i++) {
        int r = r0 + ty + i * 8, c = c0 + tx;
        float v = (r < R && c < C) ? src[(size_t)r * C + c] : 0.f;
        tile[ty + i * 8][tx] = v;
    }
    __syncthreads();
    #pragma unroll
    for (int i = 0; i < 4; i++) {
        int cc = c0 + ty + i * 8, rr = r0 + tx;
        if (cc < Crows && rr < R)
            dst[(size_t)cc * R + rr] = (__bf16)tile[tx][ty + i * 8];
    }
}

// ---------------- bf16 MFMA GEMM: C[M][N] = A[M][K] * Bt[N][K]^T ----------------
// global -> LDS staging via global_load_lds width=16 (m97 pattern)
template<int STORE_BF16>
__global__ __launch_bounds__(256) void gemm_bt_kernel(const __bf16* __restrict__ A,
                                                      const __bf16* __restrict__ Bt,
                                                      float* __restrict__ Cf,
                                                      __bf16* __restrict__ Cb,
                                                      int M, int N, int K) {
    __shared__ __align__(16) __bf16 As[128][32];
    __shared__ __align__(16) __bf16 Bs[128][32];
    const int tid = threadIdx.x;
    const int m0 = blockIdx.x * 128, n0 = blockIdx.y * 128;
    const int wave = tid >> 6, lane = tid & 63;
    const int wm = (wave & 1) << 6, wn = (wave >> 1) << 6;
    const int lm = lane & 15, lq = lane >> 4;

    floatx4 acc[4][4] = {};

    for (int k0 = 0; k0 < K; k0 += 32) {
        #pragma unroll
        for (int r = 0; r < 2; r++) {
            int c = tid + (r << 8);              // 512 chunks of 8 bf16 (16 B)
            int row = c >> 2, off = (c & 3) << 3;
            // LDS dest byte offset = c*16: wave-uniform base + lane*16  (m97 layout rule)
            __builtin_amdgcn_global_load_lds(
                reinterpret_cast<const unsigned int*>(&A[(size_t)(m0 + row) * K + k0 + off]),
                reinterpret_cast<unsigned int*>(&As[0][0] + (size_t)c * 8), 16, 0, 0);
            __builtin_amdgcn_global_load_lds(
                reinterpret_cast<const unsigned int*>(&Bt[(size_t)(n0 + row) * K + k0 + off]),
                reinterpret_cast<unsigned int*>(&Bs[0][0] + (size_t)c * 8), 16, 0, 0);
        }
        __syncthreads();
        bf16x8 af[4], bfr[4];
        #pragma unroll
        for (int i = 0; i < 4; i++)
            af[i] = *(const bf16x8*)(&As[wm + i * 16 + lm][lq * 8]);
        #pragma unroll
        for (int i = 0; i < 4; i++)
            bfr[i] = *(const bf16x8*)(&Bs[wn + i * 16 + lm][lq * 8]);
        #pragma unroll
        for (int mi = 0; mi < 4; mi++)
            #pragma unroll
            for (int ni = 0; ni < 4; ni++)
                acc[mi][ni] = __builtin_amdgcn_mfma_f32_16x16x32_bf16(af[mi], bfr[ni], acc[mi][ni], 0, 0, 0);
        __syncthreads();
    }

    #pragma unroll
    for (int mi = 0; mi < 4; mi++) {
        #pragma unroll
        for (int r = 0; r < 4; r++) {
            int row = m0 + wm + mi * 16 + lq * 4 + r;
            #pragma unroll
            for (int ni = 0; ni < 4; ni++) {
                int col = n0 + wn + ni * 16 + lm;
                if (col < N) {
                    if (STORE_BF16) Cb[(size_t)row * N + col] = (__bf16)acc[mi][ni][r];
                    else            Cf[(size_t)row * N + col] = acc[mi][ni][r];
                }
            }
        }
    }
}

// ---------------- depthwise causal conv (width 4) + silu (bf16 in/out, fp32 math) ----
__global__ __launch_bounds__(256) void conv_silu_kernel(const __bf16* __restrict__ zx,
                                                        const float* __restrict__ cw,
                                                        const float* __restrict__ cb,
                                                        __bf16* __restrict__ out) {
    int c = blockIdx.x * 256 + threadIdx.x;
    if (c >= CONVD) return;
    int g = blockIdx.y;            // (b, t-group of 4)
    int b = g >> 9;                // 512 groups per batch
    int t0 = (g & 511) << 2;
    const __bf16* base = zx + ((size_t)b * SEQ) * DPROJ + DIN + c;
    float xbuf[7];
    #pragma unroll
    for (int i = 0; i < 7; i++) {
        int tt = t0 + i - 3;
        xbuf[i] = (tt >= 0) ? (float)base[(size_t)tt * DPROJ] : 0.f;
    }
    float w0 = cw[c * 4 + 0], w1 = cw[c * 4 + 1], w2 = cw[c * 4 + 2], w3 = cw[c * 4 + 3];
    float bias = cb[c];
    __bf16* orow = out + ((size_t)b * SEQ + t0) * CONVD + c;
    #pragma unroll
    for (int s = 0; s < 4; s++) {
        float v = bias + w0 * xbuf[s] + w1 * xbuf[s + 1] + w2 * xbuf[s + 2] + w3 * xbuf[s + 3];
        orow[(size_t)s * CONVD] = (__bf16)(v / (1.f + __expf(-v)));
    }
}

// ---------------- dt prep: softplus + per-chunk inclusive cumsum of dt*A ----------------
__global__ __launch_bounds__(256) void dt_prep_kernel(const float* __restrict__ dtraw,
                                                      const float* __restrict__ dt_bias,
                                                      const float* __restrict__ A_log,
                                                      float* __restrict__ dtv,
                                                      float* __restrict__ cum) {
    int blk = blockIdx.x;          // b*NH + h
    int b = blk >> 5, h = blk & 31;
    int wave = threadIdx.x >> 6, lane = threadIdx.x & 63;
    float Ah = -__expf(A_log[h]);
    float dtb = dt_bias[h];
    for (int c = wave; c < NC; c += 4) {
        int t = c * QC + lane;
        float u = dtraw[((size_t)b * SEQ + t) * NH + h] + dtb;
        float d = fmaxf(u, 0.f) + log1pf(__expf(-fabsf(u)));  // softplus, fp32
        float s = d * Ah;
        #pragma unroll
        for (int o = 1; o < 64; o <<= 1) {        // inclusive wave prefix sum
            float v = __shfl_up(s, o);
            if (lane >= o) s += v;
        }
        size_t idx = (size_t)blk * SEQ + t;
        dtv[idx] = d;
        cum[idx] = s;
    }
}

// ---------------- pass 1: per-chunk local scan (zero init state) ----------------
__global__ __launch_bounds__(256) void scan_chunk_kernel(const __bf16* __restrict__ xc,
                                                         const float* __restrict__ dtv,
                                                         const float* __restrict__ A_log,
                                                         const float* __restrict__ Dv,
                                                         __bf16* __restrict__ y,
                                                         __bf16* __restrict__ Sbuf) {
    const int blk = blockIdx.x;          // ((b*NC)+c)*NH + h
    const int h = blk & 31;
    const int bc = blk >> 5;
    const int c = bc & (NC - 1), b = bc >> 5;
    const int tid = threadIdx.x;
    const int wave = tid >> 6, lane = tid & 63;
    const int p = wave * 16 + (lane >> 2);
    const int ng = lane & 3;
    const float Ah = -__expf(A_log[h]);
    const float Dh = Dv[h];

    __shared__ float sx[16][64], sB[16][64], sC[16][64], sdt[16];
    float hreg[16];
    #pragma unroll
    for (int i = 0; i < 16; i++) hreg[i] = 0.f;

    const __bf16* xb = xc + ((size_t)b * SEQ + (size_t)c * QC) * CONVD;
    const float* dtp = dtv + ((size_t)b * NH + h) * SEQ + (size_t)c * QC;

    for (int t0 = 0; t0 < QC; t0 += 16) {
        for (int idx = tid; idx < 16 * 192; idx += 256) {
            int s = idx / 192, j = idx % 192;
            const __bf16* rowp = xb + (size_t)(t0 + s) * CONVD;
            if (j < 64)       sx[s][j]       = (float)rowp[h * 64 + j];
            else if (j < 128) sB[s][j - 64]  = (float)rowp[DIN + (j - 64)];
            else              sC[s][j - 128] = (float)rowp[DIN + DST + (j - 128)];
        }
        if (tid < 16) sdt[tid] = dtp[t0 + tid];
        __syncthreads();
        for (int s = 0; s < 16; s++) {
            float dtt = sdt[s];
            float dA = __expf(dtt * Ah);
            float xv = sx[s][p];
            float dtx = dtt * xv;
            float ysum = 0.f;
            #pragma unroll
            for (int n = 0; n < 16; n++) {
                float Bv = sB[s][ng * 16 + n];
                float Cv = sC[s][ng * 16 + n];
                hreg[n] = fmaf(hreg[n], dA, dtx * Bv);
                ysum = fmaf(hreg[n], Cv, ysum);
            }
            ysum += __shfl_xor(ysum, 1);
            ysum += __shfl_xor(ysum, 2);
            if (ng == 0)
                y[((size_t)b * SEQ + (size_t)c * QC + t0 + s) * DIN + h * 64 + p] = (__bf16)fmaf(Dh, xv, ysum);
        }
        __syncthreads();
    }
    __bf16* Sp = Sbuf + (size_t)blk * (HD * DST) + p * DST + ng * 16;
    #pragma unroll
    for (int n = 0; n < 16; n++) Sp[n] = (__bf16)hreg[n];
}

// ---------------- pass 2: inter-chunk state recurrence (in place) ----------------
__global__ __launch_bounds__(256) void state_scan_kernel(__bf16* __restrict__ Sbuf,
                                                         const float* __restrict__ cum) {
    int blk = blockIdx.x;          // b*NH + h
    int b = blk >> 5, h = blk & 31;
    int off = threadIdx.x * 16;
    float run[16];
    #pragma unroll
    for (int n = 0; n < 16; n++) run[n] = 0.f;
    for (int c = 0; c < NC; c++) {
        __bf16* Sp = Sbuf + ((size_t)(b * NC + c) * NH + h) * (HD * DST) + off;
        float tmp[16];
        #pragma unroll
        for (int n = 0; n < 16; n++) tmp[n] = (float)Sp[n];
        #pragma unroll
        for (int n = 0; n < 16; n++) Sp[n] = (__bf16)run[n];   // slot c <- state before chunk c
        float P = __expf(cum[(size_t)blk * SEQ + c * QC + QC - 1]);
        #pragma unroll
        for (int n = 0; n < 16; n++) run[n] = fmaf(run[n], P, tmp[n]);
    }
}

// ---------------- pass 3: apply inter-chunk state to y ----------------
__global__ __launch_bounds__(256) void state_apply_kernel(const __bf16* __restrict__ Sbuf,
                                                          const __bf16* __restrict__ xc,
                                                          const float* __restrict__ cum,
                                                          __bf16* __restrict__ y) {
    const int blk = blockIdx.x;          // ((b*NC)+c)*NH + h
    const int h = blk & 31;
    const int bc = blk >> 5;
    const int c = bc & (NC - 1), b = bc >> 5;
    const int tid = threadIdx.x;
    const int wave = tid >> 6, lane = tid & 63;
    const int p = wave * 16 + (lane >> 2);
    const int ng = lane & 3;

    float S[16];
    const __bf16* Sp = Sbuf + (size_t)blk * (HD * DST) + p * DST + ng * 16;
    #pragma unroll
    for (int n = 0; n < 16; n++) S[n] = (float)Sp[n];

    __shared__ float sC[16][64], scum[16];
    const float* cump = cum + ((size_t)b * NH + h) * SEQ + (size_t)c * QC;

    for (int t0 = 0; t0 < QC; t0 += 16) {
        for (int idx = tid; idx < 16 * 64; idx += 256) {
            int s = idx >> 6, j = idx & 63;
            sC[s][j] = (float)xc[((size_t)b * SEQ + (size_t)c * QC + t0 + s) * CONVD + DIN + DST + j];
        }
        if (tid < 16) scum[tid] = cump[t0 + tid];
        __syncthreads();
        for (int s = 0; s < 16; s++) {
            float part = 0.f;
            #pragma unroll
            for (int n = 0; n < 16; n++)
                part = fmaf(S[n], sC[s][ng * 16 + n], part);
            part += __shfl_xor(part, 1);
            part += __shfl_xor(part, 2);
            if (ng == 0) {
                size_t yi = ((size_t)b * SEQ + (size_t)c * QC + t0 + s) * DIN + h * 64 + p;
                y[yi] = (__bf16)((float)y[yi] + __expf(scum[s]) * part);
            }
        }
        __syncthreads();
    }
}

// ---------------- gate (silu(z)) + RMSNorm, IN PLACE on y (bf16) ----------------
__global__ __launch_bounds__(256) void gate_norm_kernel(__bf16* __restrict__ y,
                                                        const __bf16* __restrict__ zx,
                                                        const float* __restrict__ nw) {
    int row = blockIdx.x;
    int tid = threadIdx.x;
    __bf16* yr = y + (size_t)row * DIN;
    const __bf16* zr = zx + (size_t)row * DPROJ;   // z = first 2048 cols
    float v[8]; float ss = 0.f;
    #pragma unroll
    for (int i = 0; i < 8; i++) {
        int c = i * 256 + tid;
        float z = (float)zr[c];
        float val = (float)yr[c] * (z / (1.f + __expf(-z)));
        v[i] = val; ss += val * val;
    }
    __shared__ float red[4];
    int lane = tid & 63, wave = tid >> 6;
    for (int o = 32; o > 0; o >>= 1) ss += __shfl_down(ss, o);
    if (lane == 0) red[wave] = ss;
    __syncthreads();
    float tot = red[0] + red[1] + red[2] + red[3];
    float scale = rsqrtf(tot * (1.f / (float)DIN) + 1e-5f);
    #pragma unroll
    for (int i = 0; i < 8; i++) {
        int c = i * 256 + tid;
        yr[c] = (__bf16)(v[i] * scale * nw[c]);
    }
}

// ---------------- launch ----------------
extern "C" void kernel_launch(void* const* d_in, const int* in_sizes, int n_in,
                              void* d_out, int out_size, void* d_ws, size_t ws_size,
                              hipStream_t stream) {
    const float* x       = (const float*)d_in[0];
    const float* W_in    = (const float*)d_in[1];
    const float* conv_w  = (const float*)d_in[2];
    const float* conv_b  = (const float*)d_in[3];
    const float* dt_bias = (const float*)d_in[4];
    const float* A_log   = (const float*)d_in[5];
    const float* Dv      = (const float*)d_in[6];
    const float* norm_w  = (const float*)d_in[7];
    const float* W_out   = (const float*)d_in[8];
    float* out = (float*)d_out;

    char* ws = (char*)d_ws;
    size_t off = 0;
    auto take = [&](size_t bytes) { void* p = ws + off; off = (off + bytes + 255) & ~(size_t)255; return p; };
    __bf16* xbf    = (__bf16*)take((size_t)MROWS * DM * 2);          // 16.8 MB
    __bf16* WinT   = (__bf16*)take((size_t)NPAD1 * DM * 2);          //  8.9 MB
    __bf16* WoutT  = (__bf16*)take((size_t)DM * DIN * 2);            //  4.2 MB
    __bf16* zx     = (__bf16*)take((size_t)MROWS * DPROJ * 2);       // 69.7 MB
    __bf16* xc     = (__bf16*)take((size_t)MROWS * CONVD * 2);       // 35.7 MB
    __bf16* yf     = (__bf16*)take((size_t)MROWS * DIN * 2);         // 33.6 MB
    float*  dtraw  = (float*) take((size_t)MROWS * NH * 4);          //  1.0 MB
    float*  dtv    = (float*) take((size_t)B_SZ * NH * SEQ * 4);     //  1.0 MB
    float*  cum    = (float*) take((size_t)B_SZ * NH * SEQ * 4);     //  1.0 MB
    __bf16* Sbuf   = (__bf16*)take((size_t)B_SZ * NC * NH * HD * DST * 2); // 33.6 MB
    float*  dtWc   = (float*) take((size_t)DM * NH * 4);             //  0.13 MB
    (void)ws_size;                                                    // total ~206 MB

    // 1. compact dt-weight
    dtw_prep_kernel<<<dim3(DM * NH / 256), 256, 0, stream>>>(W_in, dtWc);
    // 2. fused x->bf16 + fp32 dt projection
    cvt_dt_kernel<<<dim3(MROWS / 4), 256, 0, stream>>>(x, dtWc, xbf, dtraw);
    // 3. W_in^T (pad to 4352 rows of zeros), W_out^T
    transpose_cvt_kernel<<<dim3(DM / 32, NPAD1 / 32), 256, 0, stream>>>(W_in, WinT, DM, DPROJ, NPAD1);
    transpose_cvt_kernel<<<dim3(DIN / 32, DM / 32), 256, 0, stream>>>(W_out, WoutT, DIN, DM, DM);
    // 4. GEMM1: zx = x @ W_in  (bf16 out)
    gemm_bt_kernel<1><<<dim3(MROWS / 128, (DPROJ + 127) / 128), 256, 0, stream>>>(
        xbf, WinT, nullptr, zx, MROWS, DPROJ, DM);
    // 5. depthwise conv + silu
    conv_silu_kernel<<<dim3((CONVD + 255) / 256, B_SZ * SEQ / 4), 256, 0, stream>>>(zx, conv_w, conv_b, xc);
    // 6. dt prep: softplus + per-chunk cumsum
    dt_prep_kernel<<<dim3(B_SZ * NH), 256, 0, stream>>>(dtraw, dt_bias, A_log, dtv, cum);
    // 7. pass 1: per-chunk local scan (4096 blocks)
    scan_chunk_kernel<<<dim3(B_SZ * NC * NH), 256, 0, stream>>>(xc, dtv, A_log, Dv, yf, Sbuf);
    // 8. pass 2: inter-chunk state recurrence
    state_scan_kernel<<<dim3(B_SZ * NH), 256, 0, stream>>>(Sbuf, cum);
    // 9. pass 3: apply inter-chunk states to y
    state_apply_kernel<<<dim3(B_SZ * NC * NH), 256, 0, stream>>>(Sbuf, xc, cum, yf);
    // 10. gate + RMSNorm (in place on yf)
    gate_norm_kernel<<<dim3(MROWS), 256, 0, stream>>>(yf, zx, norm_w);
    // 11. GEMM2: out = yf @ W_out (fp32 out)
    gemm_bt_kernel<0><<<dim3(MROWS / 128, DM / 128), 256, 0, stream>>>(
        yf, WoutT, out, nullptr, MROWS, DM, DIN);
}

// Round 5
// 399.340 us; speedup vs baseline: 4.0022x; 1.3667x over previous
//
#include <hip/hip_runtime.h>
#include <hip/hip_bf16.h>

// ---------------- constants ----------------
#define B_SZ   4
#define SEQ    2048
#define DM     1024
#define DIN    2048
#define DST    64
#define NH     32
#define HD     64
#define CONVD  2176
#define DPROJ  4256   // 2*DIN + 2*DST + NH
#define NPAD1  4352   // DPROJ padded to 34*128
#define MROWS  (B_SZ*SEQ)  // 8192
#define QC     64     // scan chunk length
#define NC     (SEQ/QC)   // 32 chunks

typedef __attribute__((ext_vector_type(8))) __bf16 bf16x8;
typedef __attribute__((ext_vector_type(4))) __bf16 bf16x4;
typedef __attribute__((ext_vector_type(4))) float  floatx4;

// XOR-swizzled index into a 64x64 bf16 LDS tile: row-stride 64, 8-elem granules
// rotated by (row&7) to kill 128B-stride bank conflicts on ds_read_b128.
__device__ __forceinline__ int swz(int row, int col) {
    return row * 64 + ((((col >> 3) ^ (row & 7)) << 3) | (col & 7));
}
__device__ __forceinline__ float bfbits2f(unsigned short u) {
    return __uint_as_float(((unsigned int)u) << 16);
}
__device__ __forceinline__ unsigned short f2bfbits(float f) {
    union { __bf16 h; unsigned short u; } cv; cv.h = (__bf16)f; return cv.u;
}

// ---------------- compact dt-weight: dtWc[k*32+h] = W_in[k][4224+h] ----------------
__global__ __launch_bounds__(256) void dtw_prep_kernel(const float* __restrict__ W_in,
                                                       float* __restrict__ dtWc) {
    int idx = blockIdx.x * 256 + threadIdx.x;     // 32768 total
    int k = idx >> 5, h = idx & 31;
    dtWc[idx] = W_in[(size_t)k * DPROJ + 2 * DIN + 2 * DST + h];
}

// ---------------- fused: x -> bf16 copy + fp32 dt projection ----------------
__global__ __launch_bounds__(256) void cvt_dt_kernel(const float* __restrict__ x,
                                                     const float* __restrict__ dtWc,
                                                     __bf16* __restrict__ xbf,
                                                     float* __restrict__ dtraw) {
    __shared__ float xs[4][DM];
    __shared__ float red[4][8][32];
    const int row0 = blockIdx.x * 4;
    const int tid = threadIdx.x;
    #pragma unroll
    for (int r = 0; r < 4; r++) {
        float4 v = ((const float4*)(x + (size_t)(row0 + r) * DM))[tid];
        bf16x4 o;
        o[0] = (__bf16)v.x; o[1] = (__bf16)v.y; o[2] = (__bf16)v.z; o[3] = (__bf16)v.w;
        *(bf16x4*)(xbf + (size_t)(row0 + r) * DM + tid * 4) = o;
        xs[r][tid * 4 + 0] = v.x; xs[r][tid * 4 + 1] = v.y;
        xs[r][tid * 4 + 2] = v.z; xs[r][tid * 4 + 3] = v.w;
    }
    __syncthreads();
    const int part = tid >> 5, h = tid & 31;
    const float* wb = dtWc + part * 128 * 32 + h;
    const int kb = part * 128;
    float s0 = 0.f, s1 = 0.f, s2 = 0.f, s3 = 0.f;
    for (int j = 0; j < 128; j++) {
        float w = wb[j * 32];
        s0 = fmaf(xs[0][kb + j], w, s0);
        s1 = fmaf(xs[1][kb + j], w, s1);
        s2 = fmaf(xs[2][kb + j], w, s2);
        s3 = fmaf(xs[3][kb + j], w, s3);
    }
    red[0][part][h] = s0; red[1][part][h] = s1;
    red[2][part][h] = s2; red[3][part][h] = s3;
    __syncthreads();
    if (tid < 128) {
        int r = tid >> 5, hh = tid & 31;
        float s = 0.f;
        #pragma unroll
        for (int p = 0; p < 8; p++) s += red[r][p][hh];
        dtraw[(size_t)(row0 + r) * NH + hh] = s;
    }
}

// ---------------- transpose + cast: dst[c][r] = bf16(src[r][c]) (0 for c>=C) ----
__global__ __launch_bounds__(256) void transpose_cvt_kernel(const float* __restrict__ src,
                                                            __bf16* __restrict__ dst,
                                                            int R, int C, int Crows) {
    __shared__ float tile[32][33];
    int r0 = blockIdx.x * 32, c0 = blockIdx.y * 32;
    int tx = threadIdx.x & 31, ty = threadIdx.x >> 5;  // 32 x 8
    #pragma unroll
    for (int i = 0; i < 4; i++) {
        int r = r0 + ty + i * 8, c = c0 + tx;
        float v = (r < R && c < C) ? src[(size_t)r * C + c] : 0.f;
        tile[ty + i * 8][tx] = v;
    }
    __syncthreads();
    #pragma unroll
    for (int i = 0; i < 4; i++) {
        int cc = c0 + ty + i * 8, rr = r0 + tx;
        if (cc < Crows && rr < R)
            dst[(size_t)cc * R + rr] = (__bf16)tile[tx][ty + i * 8];
    }
}

// ---------------- bf16 MFMA GEMM: C[M][N] = A[M][K] * Bt[N][K]^T ----------------
template<int STORE_BF16>
__global__ __launch_bounds__(256) void gemm_bt_kernel(const __bf16* __restrict__ A,
                                                      const __bf16* __restrict__ Bt,
                                                      float* __restrict__ Cf,
                                                      __bf16* __restrict__ Cb,
                                                      int M, int N, int K) {
    __shared__ __align__(16) __bf16 As[128][32];
    __shared__ __align__(16) __bf16 Bs[128][32];
    const int tid = threadIdx.x;
    const int m0 = blockIdx.x * 128, n0 = blockIdx.y * 128;
    const int wave = tid >> 6, lane = tid & 63;
    const int wm = (wave & 1) << 6, wn = (wave >> 1) << 6;
    const int lm = lane & 15, lq = lane >> 4;

    floatx4 acc[4][4] = {};

    for (int k0 = 0; k0 < K; k0 += 32) {
        #pragma unroll
        for (int r = 0; r < 2; r++) {
            int c = tid + (r << 8);              // 512 chunks of 8 bf16 (16 B)
            int row = c >> 2, off = (c & 3) << 3;
            __builtin_amdgcn_global_load_lds(
                reinterpret_cast<const unsigned int*>(&A[(size_t)(m0 + row) * K + k0 + off]),
                reinterpret_cast<unsigned int*>(&As[0][0] + (size_t)c * 8), 16, 0, 0);
            __builtin_amdgcn_global_load_lds(
                reinterpret_cast<const unsigned int*>(&Bt[(size_t)(n0 + row) * K + k0 + off]),
                reinterpret_cast<unsigned int*>(&Bs[0][0] + (size_t)c * 8), 16, 0, 0);
        }
        __syncthreads();
        bf16x8 af[4], bfr[4];
        #pragma unroll
        for (int i = 0; i < 4; i++)
            af[i] = *(const bf16x8*)(&As[wm + i * 16 + lm][lq * 8]);
        #pragma unroll
        for (int i = 0; i < 4; i++)
            bfr[i] = *(const bf16x8*)(&Bs[wn + i * 16 + lm][lq * 8]);
        #pragma unroll
        for (int mi = 0; mi < 4; mi++)
            #pragma unroll
            for (int ni = 0; ni < 4; ni++)
                acc[mi][ni] = __builtin_amdgcn_mfma_f32_16x16x32_bf16(af[mi], bfr[ni], acc[mi][ni], 0, 0, 0);
        __syncthreads();
    }

    #pragma unroll
    for (int mi = 0; mi < 4; mi++) {
        #pragma unroll
        for (int r = 0; r < 4; r++) {
            int row = m0 + wm + mi * 16 + lq * 4 + r;
            #pragma unroll
            for (int ni = 0; ni < 4; ni++) {
                int col = n0 + wn + ni * 16 + lm;
                if (col < N) {
                    if (STORE_BF16) Cb[(size_t)row * N + col] = (__bf16)acc[mi][ni][r];
                    else            Cf[(size_t)row * N + col] = acc[mi][ni][r];
                }
            }
        }
    }
}

// ---------------- depthwise causal conv (width 4) + silu (bf16 in/out, fp32 math) ----
__global__ __launch_bounds__(256) void conv_silu_kernel(const __bf16* __restrict__ zx,
                                                        const float* __restrict__ cw,
                                                        const float* __restrict__ cb,
                                                        __bf16* __restrict__ out) {
    int c = blockIdx.x * 256 + threadIdx.x;
    if (c >= CONVD) return;
    int g = blockIdx.y;            // (b, t-group of 4)
    int b = g >> 9;                // 512 groups per batch
    int t0 = (g & 511) << 2;
    const __bf16* base = zx + ((size_t)b * SEQ) * DPROJ + DIN + c;
    float xbuf[7];
    #pragma unroll
    for (int i = 0; i < 7; i++) {
        int tt = t0 + i - 3;
        xbuf[i] = (tt >= 0) ? (float)base[(size_t)tt * DPROJ] : 0.f;
    }
    float w0 = cw[c * 4 + 0], w1 = cw[c * 4 + 1], w2 = cw[c * 4 + 2], w3 = cw[c * 4 + 3];
    float bias = cb[c];
    __bf16* orow = out + ((size_t)b * SEQ + t0) * CONVD + c;
    #pragma unroll
    for (int s = 0; s < 4; s++) {
        float v = bias + w0 * xbuf[s] + w1 * xbuf[s + 1] + w2 * xbuf[s + 2] + w3 * xbuf[s + 3];
        orow[(size_t)s * CONVD] = (__bf16)(v / (1.f + __expf(-v)));
    }
}

// ---------------- dt prep: softplus + per-chunk inclusive cumsum of dt*A ----------------
__global__ __launch_bounds__(256) void dt_prep_kernel(const float* __restrict__ dtraw,
                                                      const float* __restrict__ dt_bias,
                                                      const float* __restrict__ A_log,
                                                      float* __restrict__ dtv,
                                                      float* __restrict__ cum) {
    int blk = blockIdx.x;          // b*NH + h
    int b = blk >> 5, h = blk & 31;
    int wave = threadIdx.x >> 6, lane = threadIdx.x & 63;
    float Ah = -__expf(A_log[h]);
    float dtb = dt_bias[h];
    for (int c = wave; c < NC; c += 4) {
        int t = c * QC + lane;
        float u = dtraw[((size_t)b * SEQ + t) * NH + h] + dtb;
        float d = fmaxf(u, 0.f) + log1pf(__expf(-fabsf(u)));  // softplus, fp32
        float s = d * Ah;
        #pragma unroll
        for (int o = 1; o < 64; o <<= 1) {        // inclusive wave prefix sum
            float v = __shfl_up(s, o);
            if (lane >= o) s += v;
        }
        size_t idx = (size_t)blk * SEQ + t;
        dtv[idx] = d;
        cum[idx] = s;
    }
}

// ---------------- chunk state (MFMA): S^T[p][n] = sum_s x[s][p]*w_s*B[s][n] ----------
// w_s = dt_s * exp(cum_63 - cum_s).  block = (b,c,head-quad); wave = one head.
__global__ __launch_bounds__(256) void chunk_state_kernel(const __bf16* __restrict__ xc,
                                                          const float* __restrict__ dtv,
                                                          const float* __restrict__ cum,
                                                          __bf16* __restrict__ Sbuf) {
    const int blk = blockIdx.x;            // ((b*NC)+c)*8 + hq
    const int hq = blk & 7;
    const int bc = blk >> 3;
    const int c = bc & (NC - 1), b = bc >> 5;
    const int tid = threadIdx.x;
    const int wave = tid >> 6, lane = tid & 63;
    const int lm = lane & 15, q = lane >> 4;
    const int h = hq * 4 + wave;

    __shared__ __align__(16) __bf16 sBt[4096];      // B^T [n][s], swizzled
    __shared__ __align__(16) __bf16 sXw[4][4096];   // (w*x)^T [p][s], swizzled

    const size_t rowbase = (size_t)b * SEQ + (size_t)c * QC;
    // stage B^T (cooperative): thread owns s-pair (2k,2k+1), 8 n's
    {
        int k = tid & 31, n0 = (tid >> 5) * 8;
        unsigned short u0[8], u1[8];
        *(uint4*)u0 = *(const uint4*)(xc + (rowbase + 2 * k) * CONVD + DIN + n0);
        *(uint4*)u1 = *(const uint4*)(xc + (rowbase + 2 * k + 1) * CONVD + DIN + n0);
        #pragma unroll
        for (int i = 0; i < 8; i++) {
            unsigned int v = (unsigned int)u0[i] | ((unsigned int)u1[i] << 16);
            ((unsigned int*)sBt)[swz(n0 + i, 2 * k) >> 1] = v;
        }
    }
    // stage (w*x)^T per wave
    const float* cump = cum + (size_t)(b * NH + h) * SEQ + (size_t)c * QC;
    const float* dtp  = dtv + (size_t)(b * NH + h) * SEQ + (size_t)c * QC;
    {
        int k = lane & 31, ph = (lane >> 5) * 32;
        float clast = cump[63];
        float w0 = dtp[2 * k]     * __expf(clast - cump[2 * k]);
        float w1 = dtp[2 * k + 1] * __expf(clast - cump[2 * k + 1]);
        unsigned short u0[32], u1[32];
        const __bf16* r0 = xc + (rowbase + 2 * k) * CONVD + h * 64 + ph;
        const __bf16* r1 = xc + (rowbase + 2 * k + 1) * CONVD + h * 64 + ph;
        #pragma unroll
        for (int i = 0; i < 4; i++) {
            ((uint4*)u0)[i] = ((const uint4*)r0)[i];
            ((uint4*)u1)[i] = ((const uint4*)r1)[i];
        }
        unsigned int* dstw = (unsigned int*)sXw[wave];
        #pragma unroll
        for (int i = 0; i < 32; i++) {
            unsigned int lo = f2bfbits(bfbits2f(u0[i]) * w0);
            unsigned int hi = f2bfbits(bfbits2f(u1[i]) * w1);
            dstw[swz(ph + i, 2 * k) >> 1] = lo | (hi << 16);
        }
    }
    __syncthreads();

    floatx4 acc[4][4] = {};
    #pragma unroll
    for (int kb = 0; kb < 2; kb++) {
        bf16x8 aX[4], bB[4];
        #pragma unroll
        for (int pi = 0; pi < 4; pi++)
            aX[pi] = *(const bf16x8*)(&sXw[wave][swz(pi * 16 + lm, kb * 32 + q * 8)]);
        #pragma unroll
        for (int ni = 0; ni < 4; ni++)
            bB[ni] = *(const bf16x8*)(&sBt[swz(ni * 16 + lm, kb * 32 + q * 8)]);
        #pragma unroll
        for (int pi = 0; pi < 4; pi++)
            #pragma unroll
            for (int ni = 0; ni < 4; ni++)
                acc[pi][ni] = __builtin_amdgcn_mfma_f32_16x16x32_bf16(aX[pi], bB[ni], acc[pi][ni], 0, 0, 0);
    }
    __bf16* Sp = Sbuf + ((size_t)(b * NC + c) * NH + h) * (HD * DST);
    #pragma unroll
    for (int pi = 0; pi < 4; pi++)
        #pragma unroll
        for (int r = 0; r < 4; r++) {
            int p = pi * 16 + q * 4 + r;
            #pragma unroll
            for (int ni = 0; ni < 4; ni++)
                Sp[p * 64 + ni * 16 + lm] = (__bf16)acc[pi][ni][r];
        }
}

// ---------------- pass 2: inter-chunk state recurrence (in place, layout-flat) ----
__global__ __launch_bounds__(256) void state_scan_kernel(__bf16* __restrict__ Sbuf,
                                                         const float* __restrict__ cum) {
    int blk = blockIdx.x;          // b*NH + h
    int b = blk >> 5, h = blk & 31;
    int off = threadIdx.x * 16;
    float run[16];
    #pragma unroll
    for (int n = 0; n < 16; n++) run[n] = 0.f;
    for (int c = 0; c < NC; c++) {
        __bf16* Sp = Sbuf + ((size_t)(b * NC + c) * NH + h) * (HD * DST) + off;
        float tmp[16];
        #pragma unroll
        for (int n = 0; n < 16; n++) tmp[n] = (float)Sp[n];
        #pragma unroll
        for (int n = 0; n < 16; n++) Sp[n] = (__bf16)run[n];   // slot c <- state before chunk c
        float P = __expf(cum[(size_t)blk * SEQ + c * QC + QC - 1]);
        #pragma unroll
        for (int n = 0; n < 16; n++) run[n] = fmaf(run[n], P, tmp[n]);
    }
}

// ---------------- chunk output (MFMA): Y = exp(cum_t)*C@S_prev + (M o C@B^T)@X + D*x
// block = (b,c,head-pair); wave = one head; 128 threads.
__global__ __launch_bounds__(128) void chunk_out_kernel(const __bf16* __restrict__ xc,
                                                        const float* __restrict__ dtv,
                                                        const float* __restrict__ cum,
                                                        const __bf16* __restrict__ Sbuf,
                                                        const float* __restrict__ Dv,
                                                        __bf16* __restrict__ y) {
    const int blk = blockIdx.x;           // ((b*NC)+c)*16 + hp
    const int hp = blk & 15;
    const int bc = blk >> 4;
    const int c = bc & (NC - 1), b = bc >> 5;
    const int tid = threadIdx.x;
    const int wave = tid >> 6, lane = tid & 63;
    const int lm = lane & 15, q = lane >> 4;
    const int h = hp * 2 + wave;

    __shared__ __align__(16) __bf16 sC[4096];        // C [t][n] swizzled (shared)
    __shared__ __align__(16) __bf16 sB[4096];        // B [s][n] swizzled (shared)
    __shared__ __align__(16) __bf16 sXt[2][4096];    // x^T [p][s] swizzled (per wave)
    __shared__ __align__(16) __bf16 sP[2][4096];     // P [t][s] swizzled (per wave)

    const size_t rowbase = (size_t)b * SEQ + (size_t)c * QC;
    // stage C and B cooperatively: 128 threads, thread = (row, 32-col half)
    {
        int r = tid >> 1, c0 = (tid & 1) * 32;
        const __bf16* gB = xc + (rowbase + r) * CONVD + DIN + c0;
        const __bf16* gC = xc + (rowbase + r) * CONVD + DIN + DST + c0;
        #pragma unroll
        for (int i = 0; i < 4; i++) {
            *(uint4*)(&sB[swz(r, c0 + i * 8)]) = *(const uint4*)(gB + i * 8);
            *(uint4*)(&sC[swz(r, c0 + i * 8)]) = *(const uint4*)(gC + i * 8);
        }
    }
    // stage x^T per wave (pure bit move, s-pairs packed)
    {
        int k = lane & 31, ph = (lane >> 5) * 32;
        unsigned short u0[32], u1[32];
        const __bf16* r0 = xc + (rowbase + 2 * k) * CONVD + h * 64 + ph;
        const __bf16* r1 = xc + (rowbase + 2 * k + 1) * CONVD + h * 64 + ph;
        #pragma unroll
        for (int i = 0; i < 4; i++) {
            ((uint4*)u0)[i] = ((const uint4*)r0)[i];
            ((uint4*)u1)[i] = ((const uint4*)r1)[i];
        }
        unsigned int* dstw = (unsigned int*)sXt[wave];
        #pragma unroll
        for (int i = 0; i < 32; i++)
            dstw[swz(ph + i, 2 * k) >> 1] = (unsigned int)u0[i] | ((unsigned int)u1[i] << 16);
    }
    __syncthreads();

    // per-lane decay values (lane = s position)
    const float* cump = cum + (size_t)(b * NH + h) * SEQ + (size_t)c * QC;
    const float* dtp  = dtv + (size_t)(b * NH + h) * SEQ + (size_t)c * QC;
    float cumv = cump[lane], dtvv = dtp[lane];
    float ct[4][4];
    #pragma unroll
    for (int ti = 0; ti < 4; ti++)
        #pragma unroll
        for (int r = 0; r < 4; r++)
            ct[ti][r] = __shfl(cumv, ti * 16 + q * 4 + r);
    float cums_l[4], dtv_l[4];
    #pragma unroll
    for (int si = 0; si < 4; si++) {
        cums_l[si] = __shfl(cumv, si * 16 + lm);
        dtv_l[si]  = __shfl(dtvv, si * 16 + lm);
    }

    // A-fragments of C (reused for G and inter GEMMs)
    bf16x8 afC[4][2];
    #pragma unroll
    for (int ti = 0; ti < 4; ti++)
        #pragma unroll
        for (int kb = 0; kb < 2; kb++)
            afC[ti][kb] = *(const bf16x8*)(&sC[swz(ti * 16 + lm, kb * 32 + q * 8)]);

    // G = C @ B^T (triangular tiles si<=ti)
    floatx4 accG[4][4] = {};
    #pragma unroll
    for (int kb = 0; kb < 2; kb++) {
        bf16x8 bfB[4];
        #pragma unroll
        for (int si = 0; si < 4; si++)
            bfB[si] = *(const bf16x8*)(&sB[swz(si * 16 + lm, kb * 32 + q * 8)]);
        #pragma unroll
        for (int ti = 0; ti < 4; ti++)
            #pragma unroll
            for (int si = 0; si < 4; si++)
                if (si <= ti)
                    accG[ti][si] = __builtin_amdgcn_mfma_f32_16x16x32_bf16(afC[ti][kb], bfB[si], accG[ti][si], 0, 0, 0);
    }

    // mask + decay -> P (bf16, swizzled [t][s])
    __bf16* P = sP[wave];
    #pragma unroll
    for (int ti = 0; ti < 4; ti++)
        #pragma unroll
        for (int si = 0; si < 4; si++) {
            if (si > ti) continue;
            #pragma unroll
            for (int r = 0; r < 4; r++) {
                int t = ti * 16 + q * 4 + r;
                float arg = fminf(ct[ti][r] - cums_l[si], 0.f);
                float val = dtv_l[si] * __expf(arg) * accG[ti][si][r];
                if (ti == si && lm > q * 4 + r) val = 0.f;
                P[swz(t, si * 16 + lm)] = (__bf16)val;
            }
        }
    #pragma unroll
    for (int r = 0; r < 4; r++) {   // zero tiles (0,1) and (2,3)
        P[swz(q * 4 + r, 16 + lm)] = (__bf16)0.f;
        P[swz(32 + q * 4 + r, 48 + lm)] = (__bf16)0.f;
    }

    // Y accumulate: inter-chunk first (C @ S_prev), then row-scale by exp(cum_t)
    floatx4 accY[4][4] = {};
    const __bf16* Sp = Sbuf + ((size_t)(b * NC + c) * NH + h) * (HD * DST);
    #pragma unroll
    for (int kb = 0; kb < 2; kb++) {
        bf16x8 bS[4];
        #pragma unroll
        for (int pi = 0; pi < 4; pi++)
            bS[pi] = *(const bf16x8*)(Sp + (pi * 16 + lm) * 64 + kb * 32 + q * 8);
        #pragma unroll
        for (int ti = 0; ti < 4; ti++)
            #pragma unroll
            for (int pi = 0; pi < 4; pi++)
                accY[ti][pi] = __builtin_amdgcn_mfma_f32_16x16x32_bf16(afC[ti][kb], bS[pi], accY[ti][pi], 0, 0, 0);
    }
    float ert[4][4];
    #pragma unroll
    for (int ti = 0; ti < 4; ti++)
        #pragma unroll
        for (int r = 0; r < 4; r++)
            ert[ti][r] = __expf(ct[ti][r]);
    #pragma unroll
    for (int ti = 0; ti < 4; ti++)
        #pragma unroll
        for (int pi = 0; pi < 4; pi++)
            #pragma unroll
            for (int r = 0; r < 4; r++)
                accY[ti][pi][r] *= ert[ti][r];

    // intra: Y += P @ X  (skip k-blocks that are entirely masked)
    #pragma unroll
    for (int kb = 0; kb < 2; kb++) {
        bf16x8 bX[4];
        #pragma unroll
        for (int pi = 0; pi < 4; pi++)
            bX[pi] = *(const bf16x8*)(&sXt[wave][swz(pi * 16 + lm, kb * 32 + q * 8)]);
        #pragma unroll
        for (int ti = 0; ti < 4; ti++) {
            if (ti < 2 * kb) continue;
            bf16x8 aP = *(const bf16x8*)(&sP[wave][swz(ti * 16 + lm, kb * 32 + q * 8)]);
            #pragma unroll
            for (int pi = 0; pi < 4; pi++)
                accY[ti][pi] = __builtin_amdgcn_mfma_f32_16x16x32_bf16(aP, bX[pi], accY[ti][pi], 0, 0, 0);
        }
    }

    // D-term + store
    float Dh = Dv[h];
    #pragma unroll
    for (int ti = 0; ti < 4; ti++)
        #pragma unroll
        for (int r = 0; r < 4; r++) {
            int t = ti * 16 + q * 4 + r;
            __bf16* yrow = y + (rowbase + t) * DIN + h * 64;
            #pragma unroll
            for (int pi = 0; pi < 4; pi++) {
                int p = pi * 16 + lm;
                float xv = (float)sXt[wave][swz(p, t)];
                yrow[p] = (__bf16)(accY[ti][pi][r] + Dh * xv);
            }
        }
}

// ---------------- gate (silu(z)) + RMSNorm, IN PLACE on y (bf16) ----------------
__global__ __launch_bounds__(256) void gate_norm_kernel(__bf16* __restrict__ y,
                                                        const __bf16* __restrict__ zx,
                                                        const float* __restrict__ nw) {
    int row = blockIdx.x;
    int tid = threadIdx.x;
    __bf16* yr = y + (size_t)row * DIN;
    const __bf16* zr = zx + (size_t)row * DPROJ;   // z = first 2048 cols
    float v[8]; float ss = 0.f;
    #pragma unroll
    for (int i = 0; i < 8; i++) {
        int c = i * 256 + tid;
        float z = (float)zr[c];
        float val = (float)yr[c] * (z / (1.f + __expf(-z)));
        v[i] = val; ss += val * val;
    }
    __shared__ float red[4];
    int lane = tid & 63, wave = tid >> 6;
    for (int o = 32; o > 0; o >>= 1) ss += __shfl_down(ss, o);
    if (lane == 0) red[wave] = ss;
    __syncthreads();
    float tot = red[0] + red[1] + red[2] + red[3];
    float scale = rsqrtf(tot * (1.f / (float)DIN) + 1e-5f);
    #pragma unroll
    for (int i = 0; i < 8; i++) {
        int c = i * 256 + tid;
        yr[c] = (__bf16)(v[i] * scale * nw[c]);
    }
}

// ---------------- launch ----------------
extern "C" void kernel_launch(void* const* d_in, const int* in_sizes, int n_in,
                              void* d_out, int out_size, void* d_ws, size_t ws_size,
                              hipStream_t stream) {
    const float* x       = (const float*)d_in[0];
    const float* W_in    = (const float*)d_in[1];
    const float* conv_w  = (const float*)d_in[2];
    const float* conv_b  = (const float*)d_in[3];
    const float* dt_bias = (const float*)d_in[4];
    const float* A_log   = (const float*)d_in[5];
    const float* Dv      = (const float*)d_in[6];
    const float* norm_w  = (const float*)d_in[7];
    const float* W_out   = (const float*)d_in[8];
    float* out = (float*)d_out;

    char* ws = (char*)d_ws;
    size_t off = 0;
    auto take = [&](size_t bytes) { void* p = ws + off; off = (off + bytes + 255) & ~(size_t)255; return p; };
    __bf16* xbf    = (__bf16*)take((size_t)MROWS * DM * 2);          // 16.8 MB
    __bf16* WinT   = (__bf16*)take((size_t)NPAD1 * DM * 2);          //  8.9 MB
    __bf16* WoutT  = (__bf16*)take((size_t)DM * DIN * 2);            //  4.2 MB
    __bf16* zx     = (__bf16*)take((size_t)MROWS * DPROJ * 2);       // 69.7 MB
    __bf16* xc     = (__bf16*)take((size_t)MROWS * CONVD * 2);       // 35.7 MB
    __bf16* yf     = (__bf16*)take((size_t)MROWS * DIN * 2);         // 33.6 MB
    float*  dtraw  = (float*) take((size_t)MROWS * NH * 4);          //  1.0 MB
    float*  dtv    = (float*) take((size_t)B_SZ * NH * SEQ * 4);     //  1.0 MB
    float*  cum    = (float*) take((size_t)B_SZ * NH * SEQ * 4);     //  1.0 MB
    __bf16* Sbuf   = (__bf16*)take((size_t)B_SZ * NC * NH * HD * DST * 2); // 33.6 MB
    float*  dtWc   = (float*) take((size_t)DM * NH * 4);             //  0.13 MB
    (void)ws_size;                                                    // total ~206 MB

    // 1. compact dt-weight
    dtw_prep_kernel<<<dim3(DM * NH / 256), 256, 0, stream>>>(W_in, dtWc);
    // 2. fused x->bf16 + fp32 dt projection
    cvt_dt_kernel<<<dim3(MROWS / 4), 256, 0, stream>>>(x, dtWc, xbf, dtraw);
    // 3. W_in^T (pad to 4352 rows of zeros), W_out^T
    transpose_cvt_kernel<<<dim3(DM / 32, NPAD1 / 32), 256, 0, stream>>>(W_in, WinT, DM, DPROJ, NPAD1);
    transpose_cvt_kernel<<<dim3(DIN / 32, DM / 32), 256, 0, stream>>>(W_out, WoutT, DIN, DM, DM);
    // 4. GEMM1: zx = x @ W_in  (bf16 out)
    gemm_bt_kernel<1><<<dim3(MROWS / 128, (DPROJ + 127) / 128), 256, 0, stream>>>(
        xbf, WinT, nullptr, zx, MROWS, DPROJ, DM);
    // 5. depthwise conv + silu
    conv_silu_kernel<<<dim3((CONVD + 255) / 256, B_SZ * SEQ / 4), 256, 0, stream>>>(zx, conv_w, conv_b, xc);
    // 6. dt prep: softplus + per-chunk cumsum
    dt_prep_kernel<<<dim3(B_SZ * NH), 256, 0, stream>>>(dtraw, dt_bias, A_log, dtv, cum);
    // 7. chunk-local states via MFMA (1024 blocks x 4 waves)
    chunk_state_kernel<<<dim3(B_SZ * NC * (NH / 4)), 256, 0, stream>>>(xc, dtv, cum, Sbuf);
    // 8. inter-chunk state recurrence
    state_scan_kernel<<<dim3(B_SZ * NH), 256, 0, stream>>>(Sbuf, cum);
    // 9. chunk outputs via MFMA (2048 blocks x 2 waves)
    chunk_out_kernel<<<dim3(B_SZ * NC * (NH / 2)), 128, 0, stream>>>(xc, dtv, cum, Sbuf, Dv, yf);
    // 10. gate + RMSNorm (in place on yf)
    gate_norm_kernel<<<dim3(MROWS), 256, 0, stream>>>(yf, zx, norm_w);
    // 11. GEMM2: out = yf @ W_out (fp32 out)
    gemm_bt_kernel<0><<<dim3(MROWS / 128, DM / 128), 256, 0, stream>>>(
        yf, WoutT, out, nullptr, MROWS, DM, DIN);
}